// Round 4
// baseline (700.502 us; speedup 1.0000x reference)
//
#include <hip/hip_runtime.h>

#define N_NODES 50000
#define N_EDGES 1600000
#define D 48

#define EPB 8192            // edges per count/fill block
#define PB  196             // ceil(N_EDGES/EPB)
#define NPB_D 64
#define NBIN_D 782          // ceil(50000/64)
#define NPB_S 256
#define NBIN_S 196          // ceil(50000/256)

// ---------- workspace layout (bytes), total ~9.75 MB ----------
#define RECD_OFF 0          // u32[1.6M] dst-binned packed (src<<6)|dlocal
#define SRCB_OFF 6400000    // u8 [1.6M] src-binned (src & 255)
#define CI_OFF   8000000    // f32[50000]
#define CNTD_OFF 8200000    // int[PB][NBIN_D]
#define CNTS_OFF 8813120    // int[PB][NBIN_S]
#define OFFD_OFF 8966784    // int[NBIN_D][PB]
#define OFFS_OFF 9579904    // int[NBIN_S][PB]
#define TOTD_OFF 9733568    // int[NBIN_D]
#define TOTS_OFF 9736704    // int[NBIN_S]
#define BPD_OFF  9737536    // int[NBIN_D+1]
#define BPS_OFF  9740672    // int[NBIN_S+1]

__global__ __launch_bounds__(1024) void k_count(const int* __restrict__ src,
                                                const int* __restrict__ dst,
                                                int* __restrict__ cntd,
                                                int* __restrict__ cnts) {
    __shared__ int cd[NBIN_D];
    __shared__ int cs[NBIN_S];
    int tid = threadIdx.x;
    for (int i = tid; i < NBIN_D; i += 1024) cd[i] = 0;
    for (int i = tid; i < NBIN_S; i += 1024) cs[i] = 0;
    __syncthreads();
    int base = blockIdx.x * EPB;
    int end = min(base + EPB, N_EDGES);
    for (int e = base + tid; e < end; e += 1024) {
        atomicAdd(&cd[dst[e] >> 6], 1);
        atomicAdd(&cs[src[e] >> 8], 1);
    }
    __syncthreads();
    for (int i = tid; i < NBIN_D; i += 1024) cntd[blockIdx.x * NBIN_D + i] = cd[i];
    for (int i = tid; i < NBIN_S; i += 1024) cnts[blockIdx.x * NBIN_S + i] = cs[i];
}

// one block per bin: exclusive scan of per-block counts (over PB blocks)
__global__ __launch_bounds__(256) void k_binscan(const int* __restrict__ cntT, int nbin,
                                                 int* __restrict__ off, int* __restrict__ tot) {
    __shared__ int ts[256];
    int t = threadIdx.x, bin = blockIdx.x;
    int v = (t < PB) ? cntT[t * nbin + bin] : 0;
    ts[t] = v;
    __syncthreads();
    for (int o = 1; o < 256; o <<= 1) {
        int x = (t >= o) ? ts[t - o] : 0;
        __syncthreads();
        ts[t] += x;
        __syncthreads();
    }
    int incl = ts[t];
    if (t < PB) off[bin * PB + t] = incl - v;
    if (t == 255) tot[bin] = incl;
}

// single block: exclusive scan of n<=1024 bin totals -> bin_ptr[0..n]
__global__ __launch_bounds__(256) void k_scan_small(const int* __restrict__ in, int n,
                                                    int* __restrict__ out) {
    __shared__ int ts[256];
    int t = threadIdx.x;
    int base = t * 4;
    int a0 = (base + 0 < n) ? in[base + 0] : 0;
    int a1 = (base + 1 < n) ? in[base + 1] : 0;
    int a2 = (base + 2 < n) ? in[base + 2] : 0;
    int a3 = (base + 3 < n) ? in[base + 3] : 0;
    int tot4 = a0 + a1 + a2 + a3;
    ts[t] = tot4;
    __syncthreads();
    for (int o = 1; o < 256; o <<= 1) {
        int x = (t >= o) ? ts[t - o] : 0;
        __syncthreads();
        ts[t] += x;
        __syncthreads();
    }
    int excl = ts[t] - tot4;
    if (base + 0 < n) out[base + 0] = excl;
    if (base + 1 < n) out[base + 1] = excl + a0;
    if (base + 2 < n) out[base + 2] = excl + a0 + a1;
    if (base + 3 < n) out[base + 3] = excl + a0 + a1 + a2;
    if (t == 255) out[n] = ts[255];
}

__global__ __launch_bounds__(1024) void k_fill(const int* __restrict__ src,
                                               const int* __restrict__ dst,
                                               const int* __restrict__ offd,
                                               const int* __restrict__ offs,
                                               const int* __restrict__ bpd,
                                               const int* __restrict__ bps,
                                               unsigned int* __restrict__ rec,
                                               unsigned char* __restrict__ srcb) {
    __shared__ int curd[NBIN_D];
    __shared__ int curs[NBIN_S];
    int tid = threadIdx.x, blk = blockIdx.x;
    for (int i = tid; i < NBIN_D; i += 1024) curd[i] = bpd[i] + offd[i * PB + blk];
    for (int i = tid; i < NBIN_S; i += 1024) curs[i] = bps[i] + offs[i * PB + blk];
    __syncthreads();
    int base = blk * EPB;
    int end = min(base + EPB, N_EDGES);
    for (int e = base + tid; e < end; e += 1024) {
        int s = src[e], d = dst[e];
        int pd = atomicAdd(&curd[d >> 6], 1);
        rec[pd] = ((unsigned int)s << 6) | (unsigned int)(d & 63);
        int ps = atomicAdd(&curs[s >> 8], 1);
        srcb[ps] = (unsigned char)s;
    }
}

// one block per src-bin: LDS out-degree histogram -> ci
__global__ __launch_bounds__(256) void k_ci(const unsigned char* __restrict__ srcb,
                                            const int* __restrict__ bps,
                                            float* __restrict__ ci) {
    __shared__ int cnt[NPB_S];
    int t = threadIdx.x, bin = blockIdx.x;
    cnt[t] = 0;
    __syncthreads();
    int beg = bps[bin], end = bps[bin + 1];
    for (int j = beg + t; j < end; j += 256)
        atomicAdd(&cnt[srcb[j]], 1);
    __syncthreads();
    int n = bin * NPB_S + t;
    if (n < N_NODES) ci[n] = rsqrtf(fmaxf((float)cnt[t], 1.0f));
}

// one block per dst-bin: gather feat[src]*ci[src] into LDS h via ds_add_f32,
// count in-degree, then fused rescale + 48x48 GEMM + ReLU.
__global__ __launch_bounds__(256) void k_agg(
    const unsigned int* __restrict__ rec, const int* __restrict__ bpd,
    const float* __restrict__ ci, const float* __restrict__ feat,
    const float* __restrict__ W, const float* __restrict__ b,
    float* __restrict__ out) {
    __shared__ float h[NPB_D * D];     // 12.3 KB
    __shared__ float Wl[D * 49];       // 9.4 KB, stride 49
    __shared__ float bl[D];
    __shared__ int   ideg[NPB_D];
    int tid = threadIdx.x, bin = blockIdx.x;

    for (int i = tid; i < NPB_D * D; i += 256) h[i] = 0.0f;
    for (int i = tid; i < D * D; i += 256) Wl[(i / D) * 49 + (i % D)] = W[i];
    if (tid < D) bl[tid] = b[tid];
    if (tid < NPB_D) ideg[tid] = 0;
    __syncthreads();

    int wave = tid >> 6, lane = tid & 63;
    int beg = bpd[bin], end = bpd[bin + 1];
    for (int j0 = beg + wave * 64; j0 < end; j0 += 256) {
        int jn = min(64, end - j0);
        int rv = (lane < jn) ? (int)rec[j0 + lane] : 0;
        int i = 0;
        for (; i + 4 <= jn; i += 4) {
            int r0 = __shfl(rv, i), r1 = __shfl(rv, i + 1);
            int r2 = __shfl(rv, i + 2), r3 = __shfl(rv, i + 3);
            int s0 = r0 >> 6, s1 = r1 >> 6, s2 = r2 >> 6, s3 = r3 >> 6;
            if (lane < D) {
                float v0 = feat[(size_t)s0 * D + lane] * ci[s0];
                float v1 = feat[(size_t)s1 * D + lane] * ci[s1];
                float v2 = feat[(size_t)s2 * D + lane] * ci[s2];
                float v3 = feat[(size_t)s3 * D + lane] * ci[s3];
                atomicAdd(&h[(r0 & 63) * D + lane], v0);
                atomicAdd(&h[(r1 & 63) * D + lane], v1);
                atomicAdd(&h[(r2 & 63) * D + lane], v2);
                atomicAdd(&h[(r3 & 63) * D + lane], v3);
            } else if (lane == D) {
                atomicAdd(&ideg[r0 & 63], 1);
                atomicAdd(&ideg[r1 & 63], 1);
                atomicAdd(&ideg[r2 & 63], 1);
                atomicAdd(&ideg[r3 & 63], 1);
            }
        }
        for (; i < jn; ++i) {
            int r = __shfl(rv, i);
            int s = r >> 6;
            if (lane < D) {
                float v = feat[(size_t)s * D + lane] * ci[s];
                atomicAdd(&h[(r & 63) * D + lane], v);
            } else if (lane == D) {
                atomicAdd(&ideg[r & 63], 1);
            }
        }
    }
    __syncthreads();

    int nb = bin * NPB_D;
    for (int i = tid; i < NPB_D * D; i += 256) {
        int nl = i / D, k = i - nl * D;
        int n = nb + nl;
        if (n < N_NODES) {
            int dg = ideg[nl];
            h[i] = (dg > 0) ? h[i] * rsqrtf((float)dg) : feat[(size_t)n * D + k];
        }
    }
    __syncthreads();

    for (int i = tid; i < NPB_D * D; i += 256) {
        int nl = i / D, od = i - nl * D;
        int n = nb + nl;
        if (n < N_NODES) {
            float acc = bl[od];
            #pragma unroll
            for (int k = 0; k < D; ++k)
                acc = fmaf(h[nl * D + k], Wl[od * 49 + k], acc);
            out[(size_t)n * D + od] = fmaxf(acc, 0.0f);
        }
    }
}

extern "C" void kernel_launch(void* const* d_in, const int* in_sizes, int n_in,
                              void* d_out, int out_size, void* d_ws, size_t ws_size,
                              hipStream_t stream) {
    const float* feat = (const float*)d_in[0];
    const int*   src  = (const int*)d_in[1];
    const int*   dst  = (const int*)d_in[2];
    const float* W    = (const float*)d_in[3];
    const float* b    = (const float*)d_in[4];
    float* out = (float*)d_out;

    char* ws = (char*)d_ws;
    unsigned int*  rec  = (unsigned int*)(ws + RECD_OFF);
    unsigned char* srcb = (unsigned char*)(ws + SRCB_OFF);
    float* ci   = (float*)(ws + CI_OFF);
    int*   cntd = (int*)(ws + CNTD_OFF);
    int*   cnts = (int*)(ws + CNTS_OFF);
    int*   offd = (int*)(ws + OFFD_OFF);
    int*   offs = (int*)(ws + OFFS_OFF);
    int*   totd = (int*)(ws + TOTD_OFF);
    int*   tots = (int*)(ws + TOTS_OFF);
    int*   bpd  = (int*)(ws + BPD_OFF);
    int*   bps  = (int*)(ws + BPS_OFF);

    k_count<<<PB, 1024, 0, stream>>>(src, dst, cntd, cnts);
    k_binscan<<<NBIN_D, 256, 0, stream>>>(cntd, NBIN_D, offd, totd);
    k_binscan<<<NBIN_S, 256, 0, stream>>>(cnts, NBIN_S, offs, tots);
    k_scan_small<<<1, 256, 0, stream>>>(totd, NBIN_D, bpd);
    k_scan_small<<<1, 256, 0, stream>>>(tots, NBIN_S, bps);
    k_fill<<<PB, 1024, 0, stream>>>(src, dst, offd, offs, bpd, bps, rec, srcb);
    k_ci<<<NBIN_S, 256, 0, stream>>>(srcb, bps, ci);
    k_agg<<<NBIN_D, 256, 0, stream>>>(rec, bpd, ci, feat, W, b, out);
}

// Round 5
// 663.971 us; speedup vs baseline: 1.0550x; 1.0550x over previous
//
#include <hip/hip_runtime.h>

#define N_NODES 50000
#define N_EDGES 1600000
#define D 48

#define EPB 8192            // edges per count/fill block
#define PB  196             // ceil(N_EDGES/EPB)
#define NPB_D 64
#define NBIN_D 782          // ceil(50000/64)
#define NPB_S 256
#define NBIN_S 196          // ceil(50000/256)

// ---------- workspace layout (bytes), total ~9.75 MB ----------
#define RECD_OFF 0          // u32[1.6M] dst-binned packed (src<<6)|dlocal
#define SRCB_OFF 6400000    // u8 [1.6M] src-binned (src & 255)
#define CI_OFF   8000000    // f32[50000]
#define CNTD_OFF 8200000    // int[PB][NBIN_D]
#define CNTS_OFF 8813120    // int[PB][NBIN_S]
#define OFFD_OFF 8966784    // int[NBIN_D][PB]
#define OFFS_OFF 9579904    // int[NBIN_S][PB]
#define TOTD_OFF 9733568    // int[NBIN_D]
#define TOTS_OFF 9736704    // int[NBIN_S]
#define BPD_OFF  9737536    // int[NBIN_D+1]
#define BPS_OFF  9740672    // int[NBIN_S+1]

__global__ __launch_bounds__(1024) void k_count(const int* __restrict__ src,
                                                const int* __restrict__ dst,
                                                int* __restrict__ cntd,
                                                int* __restrict__ cnts) {
    __shared__ int cd[NBIN_D];
    __shared__ int cs[NBIN_S];
    int tid = threadIdx.x;
    for (int i = tid; i < NBIN_D; i += 1024) cd[i] = 0;
    for (int i = tid; i < NBIN_S; i += 1024) cs[i] = 0;
    __syncthreads();
    int base = blockIdx.x * EPB;
    int end = min(base + EPB, N_EDGES);
    for (int e = base + tid; e < end; e += 1024) {
        atomicAdd(&cd[dst[e] >> 6], 1);
        atomicAdd(&cs[src[e] >> 8], 1);
    }
    __syncthreads();
    for (int i = tid; i < NBIN_D; i += 1024) cntd[blockIdx.x * NBIN_D + i] = cd[i];
    for (int i = tid; i < NBIN_S; i += 1024) cnts[blockIdx.x * NBIN_S + i] = cs[i];
}

// one block per bin: exclusive scan of per-block counts (over PB blocks)
__global__ __launch_bounds__(256) void k_binscan(const int* __restrict__ cntT, int nbin,
                                                 int* __restrict__ off, int* __restrict__ tot) {
    __shared__ int ts[256];
    int t = threadIdx.x, bin = blockIdx.x;
    int v = (t < PB) ? cntT[t * nbin + bin] : 0;
    ts[t] = v;
    __syncthreads();
    for (int o = 1; o < 256; o <<= 1) {
        int x = (t >= o) ? ts[t - o] : 0;
        __syncthreads();
        ts[t] += x;
        __syncthreads();
    }
    int incl = ts[t];
    if (t < PB) off[bin * PB + t] = incl - v;
    if (t == 255) tot[bin] = incl;
}

// single block: exclusive scan of n<=1024 bin totals -> bin_ptr[0..n]
__global__ __launch_bounds__(256) void k_scan_small(const int* __restrict__ in, int n,
                                                    int* __restrict__ out) {
    __shared__ int ts[256];
    int t = threadIdx.x;
    int base = t * 4;
    int a0 = (base + 0 < n) ? in[base + 0] : 0;
    int a1 = (base + 1 < n) ? in[base + 1] : 0;
    int a2 = (base + 2 < n) ? in[base + 2] : 0;
    int a3 = (base + 3 < n) ? in[base + 3] : 0;
    int tot4 = a0 + a1 + a2 + a3;
    ts[t] = tot4;
    __syncthreads();
    for (int o = 1; o < 256; o <<= 1) {
        int x = (t >= o) ? ts[t - o] : 0;
        __syncthreads();
        ts[t] += x;
        __syncthreads();
    }
    int excl = ts[t] - tot4;
    if (base + 0 < n) out[base + 0] = excl;
    if (base + 1 < n) out[base + 1] = excl + a0;
    if (base + 2 < n) out[base + 2] = excl + a0 + a1;
    if (base + 3 < n) out[base + 3] = excl + a0 + a1 + a2;
    if (t == 255) out[n] = ts[255];
}

__global__ __launch_bounds__(1024) void k_fill(const int* __restrict__ src,
                                               const int* __restrict__ dst,
                                               const int* __restrict__ offd,
                                               const int* __restrict__ offs,
                                               const int* __restrict__ bpd,
                                               const int* __restrict__ bps,
                                               unsigned int* __restrict__ rec,
                                               unsigned char* __restrict__ srcb) {
    __shared__ int curd[NBIN_D];
    __shared__ int curs[NBIN_S];
    int tid = threadIdx.x, blk = blockIdx.x;
    for (int i = tid; i < NBIN_D; i += 1024) curd[i] = bpd[i] + offd[i * PB + blk];
    for (int i = tid; i < NBIN_S; i += 1024) curs[i] = bps[i] + offs[i * PB + blk];
    __syncthreads();
    int base = blk * EPB;
    int end = min(base + EPB, N_EDGES);
    for (int e = base + tid; e < end; e += 1024) {
        int s = src[e], d = dst[e];
        int pd = atomicAdd(&curd[d >> 6], 1);
        rec[pd] = ((unsigned int)s << 6) | (unsigned int)(d & 63);
        int ps = atomicAdd(&curs[s >> 8], 1);
        srcb[ps] = (unsigned char)s;
    }
}

// one block per src-bin: LDS out-degree histogram -> ci
__global__ __launch_bounds__(256) void k_ci(const unsigned char* __restrict__ srcb,
                                            const int* __restrict__ bps,
                                            float* __restrict__ ci) {
    __shared__ int cnt[NPB_S];
    int t = threadIdx.x, bin = blockIdx.x;
    cnt[t] = 0;
    __syncthreads();
    int beg = bps[bin], end = bps[bin + 1];
    for (int j = beg + t; j < end; j += 256)
        atomicAdd(&cnt[srcb[j]], 1);
    __syncthreads();
    int n = bin * NPB_S + t;
    if (n < N_NODES) ci[n] = rsqrtf(fmaxf((float)cnt[t], 1.0f));
}

// one block (16 waves) per dst-bin: gather feat[src]*ci[src] into LDS h via
// ds_add_f32, in-degree counted lane-parallel, fused rescale + GEMM + ReLU.
__global__ __launch_bounds__(1024) void k_agg(
    const unsigned int* __restrict__ rec, const int* __restrict__ bpd,
    const float* __restrict__ ci, const float* __restrict__ feat,
    const float* __restrict__ W, const float* __restrict__ b,
    float* __restrict__ out) {
    __shared__ float h[NPB_D * D];     // 12 KB
    __shared__ float Wl[D * 49];       // 9.4 KB
    __shared__ float bl[D];
    __shared__ int   ideg[NPB_D];
    int tid = threadIdx.x, bin = blockIdx.x;

    for (int i = tid; i < NPB_D * D; i += 1024) h[i] = 0.0f;
    for (int i = tid; i < D * D; i += 1024) Wl[(i / D) * 49 + (i % D)] = W[i];
    if (tid < D) bl[tid] = b[tid];
    if (tid < NPB_D) ideg[tid] = 0;
    __syncthreads();

    int wave = tid >> 6, lane = tid & 63;
    int beg = bpd[bin], end = bpd[bin + 1];
    for (int j0 = beg + wave * 64; j0 < end; j0 += 1024) {
        int jn = min(64, end - j0);
        int rv = (lane < jn) ? (int)rec[j0 + lane] : 0;
        if (lane < jn) atomicAdd(&ideg[rv & 63], 1);
        int i = 0;
        for (; i + 8 <= jn; i += 8) {
            int r0 = __shfl(rv, i + 0), r1 = __shfl(rv, i + 1);
            int r2 = __shfl(rv, i + 2), r3 = __shfl(rv, i + 3);
            int r4 = __shfl(rv, i + 4), r5 = __shfl(rv, i + 5);
            int r6 = __shfl(rv, i + 6), r7 = __shfl(rv, i + 7);
            if (lane < D) {
                int s0 = r0 >> 6, s1 = r1 >> 6, s2 = r2 >> 6, s3 = r3 >> 6;
                int s4 = r4 >> 6, s5 = r5 >> 6, s6 = r6 >> 6, s7 = r7 >> 6;
                float v0 = feat[(size_t)s0 * D + lane], c0 = ci[s0];
                float v1 = feat[(size_t)s1 * D + lane], c1 = ci[s1];
                float v2 = feat[(size_t)s2 * D + lane], c2 = ci[s2];
                float v3 = feat[(size_t)s3 * D + lane], c3 = ci[s3];
                float v4 = feat[(size_t)s4 * D + lane], c4 = ci[s4];
                float v5 = feat[(size_t)s5 * D + lane], c5 = ci[s5];
                float v6 = feat[(size_t)s6 * D + lane], c6 = ci[s6];
                float v7 = feat[(size_t)s7 * D + lane], c7 = ci[s7];
                atomicAdd(&h[(r0 & 63) * D + lane], v0 * c0);
                atomicAdd(&h[(r1 & 63) * D + lane], v1 * c1);
                atomicAdd(&h[(r2 & 63) * D + lane], v2 * c2);
                atomicAdd(&h[(r3 & 63) * D + lane], v3 * c3);
                atomicAdd(&h[(r4 & 63) * D + lane], v4 * c4);
                atomicAdd(&h[(r5 & 63) * D + lane], v5 * c5);
                atomicAdd(&h[(r6 & 63) * D + lane], v6 * c6);
                atomicAdd(&h[(r7 & 63) * D + lane], v7 * c7);
            }
        }
        for (; i < jn; ++i) {
            int r = __shfl(rv, i);
            if (lane < D) {
                int s = r >> 6;
                float v = feat[(size_t)s * D + lane] * ci[s];
                atomicAdd(&h[(r & 63) * D + lane], v);
            }
        }
    }
    __syncthreads();

    int nb = bin * NPB_D;
    for (int i = tid; i < NPB_D * D; i += 1024) {
        int nl = i / D, k = i - nl * D;
        int n = nb + nl;
        if (n < N_NODES) {
            int dg = ideg[nl];
            h[i] = (dg > 0) ? h[i] * rsqrtf((float)dg) : feat[(size_t)n * D + k];
        }
    }
    __syncthreads();

    for (int i = tid; i < NPB_D * D; i += 1024) {
        int nl = i / D, od = i - nl * D;
        int n = nb + nl;
        if (n < N_NODES) {
            float acc = bl[od];
            #pragma unroll
            for (int k = 0; k < D; ++k)
                acc = fmaf(h[nl * D + k], Wl[od * 49 + k], acc);
            out[(size_t)n * D + od] = fmaxf(acc, 0.0f);
        }
    }
}

extern "C" void kernel_launch(void* const* d_in, const int* in_sizes, int n_in,
                              void* d_out, int out_size, void* d_ws, size_t ws_size,
                              hipStream_t stream) {
    const float* feat = (const float*)d_in[0];
    const int*   src  = (const int*)d_in[1];
    const int*   dst  = (const int*)d_in[2];
    const float* W    = (const float*)d_in[3];
    const float* b    = (const float*)d_in[4];
    float* out = (float*)d_out;

    char* ws = (char*)d_ws;
    unsigned int*  rec  = (unsigned int*)(ws + RECD_OFF);
    unsigned char* srcb = (unsigned char*)(ws + SRCB_OFF);
    float* ci   = (float*)(ws + CI_OFF);
    int*   cntd = (int*)(ws + CNTD_OFF);
    int*   cnts = (int*)(ws + CNTS_OFF);
    int*   offd = (int*)(ws + OFFD_OFF);
    int*   offs = (int*)(ws + OFFS_OFF);
    int*   totd = (int*)(ws + TOTD_OFF);
    int*   tots = (int*)(ws + TOTS_OFF);
    int*   bpd  = (int*)(ws + BPD_OFF);
    int*   bps  = (int*)(ws + BPS_OFF);

    k_count<<<PB, 1024, 0, stream>>>(src, dst, cntd, cnts);
    k_binscan<<<NBIN_D, 256, 0, stream>>>(cntd, NBIN_D, offd, totd);
    k_binscan<<<NBIN_S, 256, 0, stream>>>(cnts, NBIN_S, offs, tots);
    k_scan_small<<<1, 256, 0, stream>>>(totd, NBIN_D, bpd);
    k_scan_small<<<1, 256, 0, stream>>>(tots, NBIN_S, bps);
    k_fill<<<PB, 1024, 0, stream>>>(src, dst, offd, offs, bpd, bps, rec, srcb);
    k_ci<<<NBIN_S, 256, 0, stream>>>(srcb, bps, ci);
    k_agg<<<NBIN_D, 1024, 0, stream>>>(rec, bpd, ci, feat, W, b, out);
}

// Round 6
// 205.998 us; speedup vs baseline: 3.4005x; 3.2232x over previous
//
#include <hip/hip_runtime.h>

#define N_NODES 50000
#define N_EDGES 1600000
#define D 48

#define EPB 8192            // edges per count/fill block
#define PB  196             // ceil(N_EDGES/EPB)
#define NPB_D 64
#define NBIN_D 782          // ceil(50000/64)
#define NPB_S 256
#define NBIN_S 196          // ceil(50000/256)

// ---------- workspace layout (bytes), total ~9.94 MB ----------
#define RECD_OFF 0          // u32[1.6M] dst-binned packed (src<<6)|dlocal; becomes col[] after k_csr
#define SRCB_OFF 6400000    // u8 [1.6M] src-binned (src & 255)
#define CI_OFF   8000000    // f32[50000]
#define CNTD_OFF 8200000    // int[PB][NBIN_D]
#define CNTS_OFF 8813120    // int[PB][NBIN_S]
#define OFFD_OFF 8966784    // int[NBIN_D][PB]
#define OFFS_OFF 9579904    // int[NBIN_S][PB]
#define TOTD_OFF 9733568    // int[NBIN_D]
#define TOTS_OFF 9736704    // int[NBIN_S]
#define BPD_OFF  9737536    // int[NBIN_D+1]
#define BPS_OFF  9740672    // int[NBIN_S+1]
#define RPTR_OFF 9741504    // int[50001]

__global__ __launch_bounds__(1024) void k_count(const int* __restrict__ src,
                                                const int* __restrict__ dst,
                                                int* __restrict__ cntd,
                                                int* __restrict__ cnts) {
    __shared__ int cd[NBIN_D];
    __shared__ int cs[NBIN_S];
    int tid = threadIdx.x;
    for (int i = tid; i < NBIN_D; i += 1024) cd[i] = 0;
    for (int i = tid; i < NBIN_S; i += 1024) cs[i] = 0;
    __syncthreads();
    int base = blockIdx.x * EPB;
    int end = min(base + EPB, N_EDGES);
    for (int e = base + tid; e < end; e += 1024) {
        atomicAdd(&cd[dst[e] >> 6], 1);
        atomicAdd(&cs[src[e] >> 8], 1);
    }
    __syncthreads();
    for (int i = tid; i < NBIN_D; i += 1024) cntd[blockIdx.x * NBIN_D + i] = cd[i];
    for (int i = tid; i < NBIN_S; i += 1024) cnts[blockIdx.x * NBIN_S + i] = cs[i];
}

// one block per bin: exclusive scan of per-block counts (over PB blocks)
__global__ __launch_bounds__(256) void k_binscan(const int* __restrict__ cntT, int nbin,
                                                 int* __restrict__ off, int* __restrict__ tot) {
    __shared__ int ts[256];
    int t = threadIdx.x, bin = blockIdx.x;
    int v = (t < PB) ? cntT[t * nbin + bin] : 0;
    ts[t] = v;
    __syncthreads();
    for (int o = 1; o < 256; o <<= 1) {
        int x = (t >= o) ? ts[t - o] : 0;
        __syncthreads();
        ts[t] += x;
        __syncthreads();
    }
    int incl = ts[t];
    if (t < PB) off[bin * PB + t] = incl - v;
    if (t == 255) tot[bin] = incl;
}

// single block: exclusive scan of n<=1024 bin totals -> bin_ptr[0..n]
__global__ __launch_bounds__(256) void k_scan_small(const int* __restrict__ in, int n,
                                                    int* __restrict__ out) {
    __shared__ int ts[256];
    int t = threadIdx.x;
    int base = t * 4;
    int a0 = (base + 0 < n) ? in[base + 0] : 0;
    int a1 = (base + 1 < n) ? in[base + 1] : 0;
    int a2 = (base + 2 < n) ? in[base + 2] : 0;
    int a3 = (base + 3 < n) ? in[base + 3] : 0;
    int tot4 = a0 + a1 + a2 + a3;
    ts[t] = tot4;
    __syncthreads();
    for (int o = 1; o < 256; o <<= 1) {
        int x = (t >= o) ? ts[t - o] : 0;
        __syncthreads();
        ts[t] += x;
        __syncthreads();
    }
    int excl = ts[t] - tot4;
    if (base + 0 < n) out[base + 0] = excl;
    if (base + 1 < n) out[base + 1] = excl + a0;
    if (base + 2 < n) out[base + 2] = excl + a0 + a1;
    if (base + 3 < n) out[base + 3] = excl + a0 + a1 + a2;
    if (t == 255) out[n] = ts[255];
}

__global__ __launch_bounds__(1024) void k_fill(const int* __restrict__ src,
                                               const int* __restrict__ dst,
                                               const int* __restrict__ offd,
                                               const int* __restrict__ offs,
                                               const int* __restrict__ bpd,
                                               const int* __restrict__ bps,
                                               unsigned int* __restrict__ rec,
                                               unsigned char* __restrict__ srcb) {
    __shared__ int curd[NBIN_D];
    __shared__ int curs[NBIN_S];
    int tid = threadIdx.x, blk = blockIdx.x;
    for (int i = tid; i < NBIN_D; i += 1024) curd[i] = bpd[i] + offd[i * PB + blk];
    for (int i = tid; i < NBIN_S; i += 1024) curs[i] = bps[i] + offs[i * PB + blk];
    __syncthreads();
    int base = blk * EPB;
    int end = min(base + EPB, N_EDGES);
    for (int e = base + tid; e < end; e += 1024) {
        int s = src[e], d = dst[e];
        int pd = atomicAdd(&curd[d >> 6], 1);
        rec[pd] = ((unsigned int)s << 6) | (unsigned int)(d & 63);
        int ps = atomicAdd(&curs[s >> 8], 1);
        srcb[ps] = (unsigned char)s;
    }
}

// one block per src-bin: LDS out-degree histogram -> ci
__global__ __launch_bounds__(256) void k_ci(const unsigned char* __restrict__ srcb,
                                            const int* __restrict__ bps,
                                            float* __restrict__ ci) {
    __shared__ int cnt[NPB_S];
    int t = threadIdx.x, bin = blockIdx.x;
    cnt[t] = 0;
    __syncthreads();
    int beg = bps[bin], end = bps[bin + 1];
    for (int j = beg + t; j < end; j += 256)
        atomicAdd(&cnt[srcb[j]], 1);
    __syncthreads();
    int n = bin * NPB_S + t;
    if (n < N_NODES) ci[n] = rsqrtf(fmaxf((float)cnt[t], 1.0f));
}

// one block per dst-bin: stage bin edges in LDS, count+scan in-degrees ->
// rowptr, then reorder in place (rec -> per-node-grouped col of src ids).
__global__ __launch_bounds__(256) void k_csr(unsigned int* __restrict__ rec,
                                             const int* __restrict__ bpd,
                                             int* __restrict__ rowptr) {
    __shared__ unsigned int ebuf[3072];   // bin edge count ~2048, sigma ~45; 3072 is >20 sigma
    __shared__ int ideg[NPB_D];
    __shared__ int off[NPB_D];
    __shared__ int cur[NPB_D];
    int tid = threadIdx.x, bin = blockIdx.x;
    int beg = bpd[bin], end = bpd[bin + 1];
    int cnt = end - beg;
    if (cnt > 3072) cnt = 3072;           // unreachable; guards LDS OOB
    if (tid < NPB_D) { ideg[tid] = 0; cur[tid] = 0; }
    __syncthreads();
    for (int j = tid; j < cnt; j += 256) {
        unsigned int r = rec[beg + j];
        ebuf[j] = r;
        atomicAdd(&ideg[r & 63], 1);
    }
    __syncthreads();
    if (tid < NPB_D) {
        int v = ideg[tid];
        int incl = v;
        for (int o = 1; o < 64; o <<= 1) {
            int u = __shfl_up(incl, o);
            if (tid >= o) incl += u;
        }
        int ex = incl - v;
        off[tid] = ex;
        int n = bin * NPB_D + tid;
        if (n < N_NODES) rowptr[n] = beg + ex;
    }
    if (bin == NBIN_D - 1 && tid == 0) rowptr[N_NODES] = N_EDGES;
    __syncthreads();
    for (int j = tid; j < cnt; j += 256) {
        unsigned int r = ebuf[j];
        int dl = r & 63;
        int p = atomicAdd(&cur[dl], 1);
        rec[beg + off[dl] + p] = r >> 6;   // now plain src id
    }
}

// one wave per dst node: register-accumulating gather, fused GEMM + ReLU
__global__ __launch_bounds__(256) void k_gcn(
    const int* __restrict__ rowptr, const int* __restrict__ col,
    const float* __restrict__ ci, const float* __restrict__ feat,
    const float* __restrict__ W, const float* __restrict__ b,
    float* __restrict__ out) {
    __shared__ float Wl[D * 49];
    __shared__ float bl[D];
    __shared__ float hl[4 * 49];
    int tid = threadIdx.x;

    for (int i = tid; i < D * D; i += 256) {
        int od = i / D, k = i - od * D;
        Wl[od * 49 + k] = W[i];
    }
    if (tid < D) bl[tid] = b[tid];

    int wave = tid >> 6;
    int lane = tid & 63;
    int n = blockIdx.x * 4 + wave;
    int kk = (lane < D) ? lane : 0;

    int beg = 0, end = 0;
    if (n < N_NODES) { beg = rowptr[n]; end = rowptr[n + 1]; }

    float acc = 0.0f;
    int j = beg;
    for (; j + 8 <= end; j += 8) {
        int s0 = col[j + 0], s1 = col[j + 1], s2 = col[j + 2], s3 = col[j + 3];
        int s4 = col[j + 4], s5 = col[j + 5], s6 = col[j + 6], s7 = col[j + 7];
        float c0 = ci[s0], c1 = ci[s1], c2 = ci[s2], c3 = ci[s3];
        float c4 = ci[s4], c5 = ci[s5], c6 = ci[s6], c7 = ci[s7];
        acc += feat[(size_t)s0 * D + kk] * c0;
        acc += feat[(size_t)s1 * D + kk] * c1;
        acc += feat[(size_t)s2 * D + kk] * c2;
        acc += feat[(size_t)s3 * D + kk] * c3;
        acc += feat[(size_t)s4 * D + kk] * c4;
        acc += feat[(size_t)s5 * D + kk] * c5;
        acc += feat[(size_t)s6 * D + kk] * c6;
        acc += feat[(size_t)s7 * D + kk] * c7;
    }
    for (; j < end; ++j) {
        int s = col[j];
        acc += feat[(size_t)s * D + kk] * ci[s];
    }

    float res = 0.0f;
    if (n < N_NODES) {
        int indeg = end - beg;
        res = (indeg > 0) ? acc * rsqrtf((float)indeg)
                          : feat[(size_t)n * D + kk];
    }
    if (lane < D) hl[wave * 49 + lane] = res;
    __syncthreads();

    if (tid < 4 * D) {
        int nl = tid / D, od = tid - nl * D;
        int n2 = blockIdx.x * 4 + nl;
        if (n2 < N_NODES) {
            float a2 = bl[od];
            #pragma unroll
            for (int k = 0; k < D; k++)
                a2 = fmaf(hl[nl * 49 + k], Wl[od * 49 + k], a2);
            out[(size_t)n2 * D + od] = fmaxf(a2, 0.0f);
        }
    }
}

extern "C" void kernel_launch(void* const* d_in, const int* in_sizes, int n_in,
                              void* d_out, int out_size, void* d_ws, size_t ws_size,
                              hipStream_t stream) {
    const float* feat = (const float*)d_in[0];
    const int*   src  = (const int*)d_in[1];
    const int*   dst  = (const int*)d_in[2];
    const float* W    = (const float*)d_in[3];
    const float* b    = (const float*)d_in[4];
    float* out = (float*)d_out;

    char* ws = (char*)d_ws;
    unsigned int*  rec  = (unsigned int*)(ws + RECD_OFF);
    unsigned char* srcb = (unsigned char*)(ws + SRCB_OFF);
    float* ci   = (float*)(ws + CI_OFF);
    int*   cntd = (int*)(ws + CNTD_OFF);
    int*   cnts = (int*)(ws + CNTS_OFF);
    int*   offd = (int*)(ws + OFFD_OFF);
    int*   offs = (int*)(ws + OFFS_OFF);
    int*   totd = (int*)(ws + TOTD_OFF);
    int*   tots = (int*)(ws + TOTS_OFF);
    int*   bpd  = (int*)(ws + BPD_OFF);
    int*   bps  = (int*)(ws + BPS_OFF);
    int*   rptr = (int*)(ws + RPTR_OFF);

    k_count<<<PB, 1024, 0, stream>>>(src, dst, cntd, cnts);
    k_binscan<<<NBIN_D, 256, 0, stream>>>(cntd, NBIN_D, offd, totd);
    k_binscan<<<NBIN_S, 256, 0, stream>>>(cnts, NBIN_S, offs, tots);
    k_scan_small<<<1, 256, 0, stream>>>(totd, NBIN_D, bpd);
    k_scan_small<<<1, 256, 0, stream>>>(tots, NBIN_S, bps);
    k_fill<<<PB, 1024, 0, stream>>>(src, dst, offd, offs, bpd, bps, rec, srcb);
    k_ci<<<NBIN_S, 256, 0, stream>>>(srcb, bps, ci);
    k_csr<<<NBIN_D, 256, 0, stream>>>(rec, bpd, rptr);
    k_gcn<<<(N_NODES + 3) / 4, 256, 0, stream>>>(rptr, (const int*)rec, ci, feat, W, b, out);
}